// Round 1
// baseline (1811.847 us; speedup 1.0000x reference)
//
#include <hip/hip_runtime.h>
#include <hip/hip_bf16.h>
#include <math.h>

#define NS 262144            // 64^3
#define TWO_PI 6.283185307179586f

__device__ __forceinline__ float gelu_(float x) {
    return 0.5f * x * (1.0f + erff(x * 0.70710678118654752f));
}

// ---------------- FiLM conditioner ----------------
__global__ void k_film1(const float* __restrict__ latent, const float* __restrict__ w,
                        const float* __restrict__ b, float* __restrict__ h) {
    int j = blockIdx.x * 256 + threadIdx.x;
    if (j >= 1024) return;
    float acc = b[j];
    const float* wr = w + j * 512;
    for (int k = 0; k < 512; k++) acc += latent[k] * wr[k];
    h[j] = gelu_(acc);
}

__global__ void k_film2(const float* __restrict__ h, const float* __restrict__ w,
                        const float* __restrict__ b, float* __restrict__ film) {
    int j = blockIdx.x * 256 + threadIdx.x;
    if (j >= 384) return;
    float acc = b[j];
    const float* wr = w + j * 1024;
    for (int k = 0; k < 1024; k++) acc += h[k] * wr[k];
    film[j] = acc;
}

// ---------------- lift: (4,NS) -> (64,NS) ----------------
__global__ void k_lift(const float* __restrict__ x, float* __restrict__ v,
                       const float* __restrict__ lw, const float* __restrict__ lb) {
    __shared__ float W[256];
    __shared__ float B[64];
    if (threadIdx.x < 256) W[threadIdx.x] = lw[threadIdx.x];
    if (threadIdx.x < 64) B[threadIdx.x] = lb[threadIdx.x];
    __syncthreads();
    int s = blockIdx.x * 256 + threadIdx.x;
    float x0 = x[s], x1 = x[NS + s], x2 = x[2 * NS + s], x3 = x[3 * NS + s];
#pragma unroll
    for (int c = 0; c < 64; c++) {
        v[c * NS + s] = W[c * 4] * x0 + W[c * 4 + 1] * x1 + W[c * 4 + 2] * x2 + W[c * 4 + 3] * x3 + B[c];
    }
}

// twiddle table helper: tw[t] = (cos, sin) of +2*pi*t/64
#define INIT_TW \
    __shared__ float2 tw[64]; \
    if (threadIdx.x < 64) { \
        float s_, c_; \
        sincosf(TWO_PI * (float)threadIdx.x * (1.0f / 64.0f), &s_, &c_); \
        tw[threadIdx.x] = make_float2(c_, s_); \
    } \
    __syncthreads();

// ---------------- forward partial DFT, W axis: v(row,64) -> A(row,12) ----------------
__global__ void k_fwd_w(const float* __restrict__ v, float2* __restrict__ A) {
    INIT_TW
    int flat = blockIdx.x * 256 + threadIdx.x;       // 262144*12
    int row = flat / 12, kw = flat - row * 12;
    const float* base = v + row * 64;
    float re = 0.f, im = 0.f;
#pragma unroll
    for (int w = 0; w < 64; w++) {
        float2 t = tw[(kw * w) & 63];
        float xv = base[w];
        re += xv * t.x;
        im -= xv * t.y;                               // e^{-i theta}
    }
    A[flat] = make_float2(re, im);
}

// ---------------- forward H axis: A(cd,64h,12) -> B(cd,24kh,12) ----------------
__global__ void k_fwd_h(const float2* __restrict__ A, float2* __restrict__ B) {
    INIT_TW
    int flat = blockIdx.x * 256 + threadIdx.x;       // 4096*24*12
    int cd = flat / 288;
    int r = flat - cd * 288;
    int kh = r / 12, kw = r - kh * 12;
    int khf = kh < 12 ? kh : kh + 40;                // 12..23 -> 52..63
    const float2* base = A + cd * 768 + kw;
    float re = 0.f, im = 0.f;
    for (int h = 0; h < 64; h++) {
        float2 a = base[h * 12];
        float2 t = tw[(khf * h) & 63];
        re += a.x * t.x + a.y * t.y;                 // a * e^{-i theta}
        im += a.y * t.x - a.x * t.y;
    }
    B[flat] = make_float2(re, im);
}

// ---------------- forward D axis: B(c,64d,24,12) -> Xf(c,24kd,24,12) ----------------
__global__ void k_fwd_d(const float2* __restrict__ B, float2* __restrict__ Xf) {
    INIT_TW
    int flat = blockIdx.x * 256 + threadIdx.x;       // 64*24*24*12
    int c = flat / 6912;
    int r = flat - c * 6912;
    int kd = r / 288;
    int r2 = r - kd * 288;
    int kdf = kd < 12 ? kd : kd + 40;
    const float2* base = B + c * 18432 + r2;
    float re = 0.f, im = 0.f;
    for (int d = 0; d < 64; d++) {
        float2 a = base[d * 288];
        float2 t = tw[(kdf * d) & 63];
        re += a.x * t.x + a.y * t.y;
        im += a.y * t.x - a.x * t.y;
    }
    Xf[flat] = make_float2(re, im);
}

// ---------------- per-mode CxC complex matvec ----------------
__global__ void k_modemul(const float2* __restrict__ Xf, float2* __restrict__ Yf,
                          const float2* __restrict__ w1, const float2* __restrict__ w2,
                          const float2* __restrict__ w3, const float2* __restrict__ w4) {
    int flat = blockIdx.x * 256 + threadIdx.x;       // 64*6912
    int o = flat / 6912;
    int mode = flat - o * 6912;
    int kd = mode / 288;
    int r2 = mode - kd * 288;
    int kh = r2 / 12, kw = r2 - kh * 12;
    const float2* wsel = (kd < 12) ? ((kh < 12) ? w1 : w3) : ((kh < 12) ? w2 : w4);
    int xi = kd < 12 ? kd : kd - 12;
    int yi = kh < 12 ? kh : kh - 12;
    const float2* wbase = wsel + (size_t)o * 1728 + xi * 144 + yi * 12 + kw;
    const float2* xbase = Xf + mode;
    float re = 0.f, im = 0.f;
    for (int i = 0; i < 64; i++) {
        float2 xv = xbase[i * 6912];
        float2 wv = wbase[(size_t)i * 110592];       // stride C*1728 float2
        re += xv.x * wv.x - xv.y * wv.y;
        im += xv.x * wv.y + xv.y * wv.x;
    }
    Yf[flat] = make_float2(re, im);
}

// ---------------- inverse D axis: Yf(o,24kd,24,12) -> Zd(o,64d,24,12) ----------------
__global__ void k_inv_d(const float2* __restrict__ Yf, float2* __restrict__ Zd) {
    INIT_TW
    int flat = blockIdx.x * 256 + threadIdx.x;       // 64*64*24*12
    int od = flat / 288;
    int r2 = flat - od * 288;
    int o = od >> 6, d = od & 63;
    const float2* base = Yf + o * 6912 + r2;
    float re = 0.f, im = 0.f;
    for (int kd = 0; kd < 24; kd++) {
        float2 z = base[kd * 288];
        int kdf = kd < 12 ? kd : kd + 40;
        float2 t = tw[(kdf * d) & 63];
        re += z.x * t.x - z.y * t.y;                 // z * e^{+i theta}
        im += z.x * t.y + z.y * t.x;
    }
    Zd[flat] = make_float2(re, im);
}

// ---------------- inverse H axis: Zd(od,24kh,12) -> Zh(od,64h,12) ----------------
__global__ void k_inv_h(const float2* __restrict__ Zd, float2* __restrict__ Zh) {
    INIT_TW
    int flat = blockIdx.x * 256 + threadIdx.x;       // 4096*64*12
    int odh = flat / 12;
    int kw = flat - odh * 12;
    int od = odh >> 6, h = odh & 63;
    const float2* base = Zd + od * 288 + kw;
    float re = 0.f, im = 0.f;
    for (int kh = 0; kh < 24; kh++) {
        float2 z = base[kh * 12];
        int khf = kh < 12 ? kh : kh + 40;
        float2 t = tw[(khf * h) & 63];
        re += z.x * t.x - z.y * t.y;
        im += z.x * t.y + z.y * t.x;
    }
    Zh[flat] = make_float2(re, im);
}

// ---------------- inverse W (irfft, drops Im of DC bin) + 1/N scale ----------------
__global__ void k_inv_w(const float2* __restrict__ Zh, float* __restrict__ x1) {
    INIT_TW
    int s = blockIdx.x * 256 + threadIdx.x;          // 16,777,216
    int row = s >> 6, w = s & 63;
    const float2* base = Zh + row * 12;
    float acc = base[0].x;                            // Re only (pocketfft c2r semantics)
#pragma unroll
    for (int kw = 1; kw < 12; kw++) {
        float2 z = base[kw];
        float2 t = tw[(kw * w) & 63];
        acc += 2.0f * (z.x * t.x - z.y * t.y);
    }
    x1[s] = acc * (1.0f / 262144.0f);
}

// ---------------- 1x1 conv, accumulate into x1 ----------------
__global__ void k_conv_add(const float* __restrict__ v, float* __restrict__ x1,
                           const float* __restrict__ w, const float* __restrict__ b) {
    __shared__ float Wl[4096];
    __shared__ float Bl[64];
    for (int i = threadIdx.x; i < 4096; i += 256) Wl[i] = w[i];
    if (threadIdx.x < 64) Bl[threadIdx.x] = b[threadIdx.x];
    __syncthreads();
    int s = blockIdx.x * 256 + threadIdx.x;
    float acc[64];
#pragma unroll
    for (int o = 0; o < 64; o++) acc[o] = 0.f;
    for (int i = 0; i < 64; i += 4) {
        float vi0 = v[i * NS + s];
        float vi1 = v[(i + 1) * NS + s];
        float vi2 = v[(i + 2) * NS + s];
        float vi3 = v[(i + 3) * NS + s];
#pragma unroll
        for (int o = 0; o < 64; o++) {
            float4 w4 = *(const float4*)&Wl[o * 64 + i];
            acc[o] += w4.x * vi0 + w4.y * vi1 + w4.z * vi2 + w4.w * vi3;
        }
    }
#pragma unroll
    for (int o = 0; o < 64; o++) x1[o * NS + s] += acc[o] + Bl[o];
}

// ---------------- GroupNorm stats: per-group sum / sumsq ----------------
__global__ void k_gn_stats(const float* __restrict__ x1, float* __restrict__ stats) {
    int g = blockIdx.x >> 8, j = blockIdx.x & 255;   // 8 groups x 256 blocks
    const float* base = x1 + ((size_t)g << 21) + j * 8192;
    float s = 0.f, s2 = 0.f;
    for (int k = 0; k < 32; k++) {
        float val = base[k * 256 + threadIdx.x];
        s += val;
        s2 += val * val;
    }
    for (int off = 32; off > 0; off >>= 1) {
        s += __shfl_down(s, off);
        s2 += __shfl_down(s2, off);
    }
    __shared__ float ls[4], ls2[4];
    int wid = threadIdx.x >> 6, lid = threadIdx.x & 63;
    if (lid == 0) { ls[wid] = s; ls2[wid] = s2; }
    __syncthreads();
    if (threadIdx.x == 0) {
        atomicAdd(&stats[g * 2], ls[0] + ls[1] + ls[2] + ls[3]);
        atomicAdd(&stats[g * 2 + 1], ls2[0] + ls2[1] + ls2[2] + ls2[3]);
    }
}

// ---------------- GroupNorm apply + GELU + FiLM -> v ----------------
__global__ void k_gn_apply(const float* __restrict__ x1, float* __restrict__ v,
                           const float* __restrict__ stats, const float* __restrict__ gg,
                           const float* __restrict__ gb, const float* __restrict__ film) {
    int idx = blockIdx.x * 256 + threadIdx.x;        // 16,777,216
    int c = idx >> 18;
    int g = c >> 3;
    float mean = stats[g * 2] * (1.0f / 2097152.0f);
    float var = stats[g * 2 + 1] * (1.0f / 2097152.0f) - mean * mean;
    float inv = rsqrtf(var + 1e-5f);
    float y = (x1[idx] - mean) * inv * gg[c] + gb[c];
    y = gelu_(y);
    float sc = film[c * 2], sh = film[c * 2 + 1];
    v[idx] = y * (1.0f + sc) + sh;
}

// ---------------- fused p1 -> GELU -> p2 epilogue ----------------
__global__ void k_p1p2(const float* __restrict__ v, float* __restrict__ out,
                       const float* __restrict__ w1, const float* __restrict__ b1,
                       const float* __restrict__ w2, const float* __restrict__ b2) {
    __shared__ float W1[8192];
    __shared__ float B1[128];
    __shared__ float W2[384];
    for (int i = threadIdx.x; i < 8192; i += 256) W1[i] = w1[i];
    if (threadIdx.x < 128) B1[threadIdx.x] = b1[threadIdx.x];
    if (threadIdx.x < 384 - 256) {}                  // keep simple: load W2 below
    for (int i = threadIdx.x; i < 384; i += 256) W2[i] = w2[i];
    __syncthreads();
    int s = blockIdx.x * 256 + threadIdx.x;
    float vv[64];
#pragma unroll
    for (int c = 0; c < 64; c++) vv[c] = v[c * NS + s];
    float a0 = b2[0], a1 = b2[1], a2 = b2[2];
    for (int j = 0; j < 128; j++) {
        float t = B1[j];
        const float* wr = &W1[j * 64];
#pragma unroll
        for (int c = 0; c < 64; c += 4) {
            float4 w4 = *(const float4*)&wr[c];
            t += w4.x * vv[c] + w4.y * vv[c + 1] + w4.z * vv[c + 2] + w4.w * vv[c + 3];
        }
        t = gelu_(t);
        a0 += t * W2[j];
        a1 += t * W2[128 + j];
        a2 += t * W2[256 + j];
    }
    out[s] = a0;
    out[NS + s] = a1;
    out[2 * NS + s] = a2;
}

extern "C" void kernel_launch(void* const* d_in, const int* in_sizes, int n_in,
                              void* d_out, int out_size, void* d_ws, size_t ws_size,
                              hipStream_t stream) {
    const float* x      = (const float*)d_in[0];
    const float* latent = (const float*)d_in[1];
    const float* lift_w = (const float*)d_in[2];
    const float* lift_b = (const float*)d_in[3];
    const float* sc_w1  = (const float*)d_in[4];
    const float* sc_w2  = (const float*)d_in[5];
    const float* sc_w3  = (const float*)d_in[6];
    const float* sc_w4  = (const float*)d_in[7];
    const float* conv_w = (const float*)d_in[8];
    const float* conv_b = (const float*)d_in[9];
    const float* gn_g   = (const float*)d_in[10];
    const float* gn_b   = (const float*)d_in[11];
    const float* p1_w   = (const float*)d_in[12];
    const float* p1_b   = (const float*)d_in[13];
    const float* p2_w   = (const float*)d_in[14];
    const float* p2_b   = (const float*)d_in[15];
    const float* c1_w   = (const float*)d_in[16];
    const float* c1_b   = (const float*)d_in[17];
    const float* c2_w   = (const float*)d_in[18];
    const float* c2_b   = (const float*)d_in[19];

    float* ws = (float*)d_ws;
    float*  v    = ws;                                // 16,777,216
    float*  x1   = ws + 16777216;                     // 16,777,216
    float2* A    = (float2*)(ws + 33554432);          // 3,145,728 f2 (A / Zh shared)
    float2* Bc   = (float2*)(ws + 39845888);          // 1,179,648 f2 (B / Zd shared)
    float2* Xf   = (float2*)(ws + 42205184);          // 442,368 f2
    float2* Yf   = (float2*)(ws + 43089920);          // 442,368 f2
    float*  hbuf = ws + 43974656;                     // 1024
    float*  film = ws + 43975680;                     // 384
    float*  stats= ws + 43976064;                     // 48

    hipMemsetAsync(stats, 0, 48 * sizeof(float), stream);
    k_film1<<<4, 256, 0, stream>>>(latent, c1_w, c1_b, hbuf);
    k_film2<<<2, 256, 0, stream>>>(hbuf, c2_w, c2_b, film);
    k_lift<<<1024, 256, 0, stream>>>(x, v, lift_w, lift_b);

    for (int l = 0; l < 3; l++) {
        size_t woff = (size_t)l * 64 * 64 * 1728;     // float2 units per layer
        k_fwd_w<<<12288, 256, 0, stream>>>(v, A);
        k_fwd_h<<<4608, 256, 0, stream>>>(A, Bc);
        k_fwd_d<<<1728, 256, 0, stream>>>(Bc, Xf);
        k_modemul<<<1728, 256, 0, stream>>>(Xf, Yf,
            (const float2*)sc_w1 + woff, (const float2*)sc_w2 + woff,
            (const float2*)sc_w3 + woff, (const float2*)sc_w4 + woff);
        k_inv_d<<<4608, 256, 0, stream>>>(Yf, Bc);
        k_inv_h<<<12288, 256, 0, stream>>>(Bc, A);
        k_inv_w<<<65536, 256, 0, stream>>>(A, x1);
        k_conv_add<<<1024, 256, 0, stream>>>(v, x1, conv_w + l * 4096, conv_b + l * 64);
        k_gn_stats<<<2048, 256, 0, stream>>>(x1, stats + l * 16);
        k_gn_apply<<<65536, 256, 0, stream>>>(x1, v, stats + l * 16,
                                              gn_g + l * 64, gn_b + l * 64, film + l * 128);
    }
    k_p1p2<<<1024, 256, 0, stream>>>(v, (float*)d_out, p1_w, p1_b, p2_w, p2_b);
}

// Round 2
// 1790.513 us; speedup vs baseline: 1.0119x; 1.0119x over previous
//
#include <hip/hip_runtime.h>
#include <hip/hip_bf16.h>
#include <math.h>

#define NS 262144            // 64^3
#define STEP64 0.09817477042468103f   // 2*pi/64

__device__ __forceinline__ float gelu_(float x) {
    return 0.5f * x * (1.0f + erff(x * 0.70710678118654752f));
}
__device__ __forceinline__ float2 cmul_(float2 a, float2 b) {
    return make_float2(a.x * b.x - a.y * b.y, a.x * b.y + a.y * b.x);
}

// ---------------- FiLM conditioner ----------------
__global__ void k_film1(const float* __restrict__ latent, const float* __restrict__ w,
                        const float* __restrict__ b, float* __restrict__ h) {
    int j = blockIdx.x * 256 + threadIdx.x;
    if (j >= 1024) return;
    float acc = b[j];
    const float* wr = w + j * 512;
    for (int k = 0; k < 512; k++) acc += latent[k] * wr[k];
    h[j] = gelu_(acc);
}

__global__ void k_film2(const float* __restrict__ h, const float* __restrict__ w,
                        const float* __restrict__ b, float* __restrict__ film) {
    int j = blockIdx.x * 256 + threadIdx.x;
    if (j >= 384) return;
    float acc = b[j];
    const float* wr = w + j * 1024;
    for (int k = 0; k < 1024; k++) acc += h[k] * wr[k];
    film[j] = acc;
}

// ---------------- lift: (4,NS) -> (64,NS); weights via uniform (scalar) loads ----
__global__ void k_lift(const float* __restrict__ x, float* __restrict__ v,
                       const float* __restrict__ lw, const float* __restrict__ lb) {
    int s = blockIdx.x * 256 + threadIdx.x;
    float x0 = x[s], x1 = x[NS + s], x2 = x[2 * NS + s], x3 = x[3 * NS + s];
#pragma unroll
    for (int c = 0; c < 64; c++) {
        float4 wc = *(const float4*)(lw + c * 4);   // uniform -> s_load
        v[c * NS + s] = wc.x * x0 + wc.y * x1 + wc.z * x2 + wc.w * x3 + lb[c];
    }
}

// ---------------- forward partial DFT, W axis: v(row,64) -> A(row,12) ----------------
// twiddle via register recurrence: t_{w+1} = t_w * e^{-i*2pi*kw/64}
__global__ void k_fwd_w(const float* __restrict__ v, float2* __restrict__ A) {
    int flat = blockIdx.x * 256 + threadIdx.x;       // 3,145,728
    int row = flat / 12, kw = flat - row * 12;
    const float4* base = (const float4*)(v + row * 64);
    float sn, cn;
    sincosf((float)kw * STEP64, &sn, &cn);
    float2 st = make_float2(cn, -sn);                // e^{-i theta}
    float2 t = make_float2(1.f, 0.f);
    float re = 0.f, im = 0.f;
#pragma unroll
    for (int w4 = 0; w4 < 16; w4++) {
        float4 xv = base[w4];
        re += xv.x * t.x; im += xv.x * t.y; t = cmul_(t, st);
        re += xv.y * t.x; im += xv.y * t.y; t = cmul_(t, st);
        re += xv.z * t.x; im += xv.z * t.y; t = cmul_(t, st);
        re += xv.w * t.x; im += xv.w * t.y; t = cmul_(t, st);
    }
    A[flat] = make_float2(re, im);
}

// ---------------- forward H axis: A(cd,64h,12) -> B(cd,24kh,12) ----------------
__global__ void k_fwd_h(const float2* __restrict__ A, float2* __restrict__ B) {
    int flat = blockIdx.x * 256 + threadIdx.x;       // 1,179,648
    int cd = flat / 288;
    int r = flat - cd * 288;
    int kh = r / 12, kw = r - kh * 12;
    int khf = kh < 12 ? kh : kh + 40;
    const float2* base = A + cd * 768 + kw;
    float sn, cn;
    sincosf((float)khf * STEP64, &sn, &cn);
    float2 st = make_float2(cn, -sn);
    float2 t = make_float2(1.f, 0.f);
    float re = 0.f, im = 0.f;
#pragma unroll 8
    for (int h = 0; h < 64; h++) {
        float2 a = base[h * 12];
        re += a.x * t.x - a.y * t.y;
        im += a.x * t.y + a.y * t.x;
        t = cmul_(t, st);
    }
    B[flat] = make_float2(re, im);
}

// ---------------- forward D axis: B(c,64d,24,12) -> Xf(c,24kd,24,12) ----------------
__global__ void k_fwd_d(const float2* __restrict__ B, float2* __restrict__ Xf) {
    int flat = blockIdx.x * 256 + threadIdx.x;       // 442,368
    int c = flat / 6912;
    int r = flat - c * 6912;
    int kd = r / 288;
    int r2 = r - kd * 288;
    int kdf = kd < 12 ? kd : kd + 40;
    const float2* base = B + c * 18432 + r2;
    float sn, cn;
    sincosf((float)kdf * STEP64, &sn, &cn);
    float2 st = make_float2(cn, -sn);
    float2 t = make_float2(1.f, 0.f);
    float re = 0.f, im = 0.f;
#pragma unroll 8
    for (int d = 0; d < 64; d++) {
        float2 a = base[d * 288];
        re += a.x * t.x - a.y * t.y;
        im += a.x * t.y + a.y * t.x;
        t = cmul_(t, st);
    }
    Xf[flat] = make_float2(re, im);
}

// ---------------- per-mode CxC complex matvec (streams 226 MB/layer of weights) ----
__global__ void k_modemul(const float2* __restrict__ Xf, float2* __restrict__ Yf,
                          const float2* __restrict__ w1, const float2* __restrict__ w2,
                          const float2* __restrict__ w3, const float2* __restrict__ w4) {
    int flat = blockIdx.x * 256 + threadIdx.x;       // 442,368
    int o = flat / 6912;
    int mode = flat - o * 6912;
    int kd = mode / 288;
    int r2 = mode - kd * 288;
    int kh = r2 / 12, kw = r2 - kh * 12;
    const float2* wsel = (kd < 12) ? ((kh < 12) ? w1 : w3) : ((kh < 12) ? w2 : w4);
    int xi = kd < 12 ? kd : kd - 12;
    int yi = kh < 12 ? kh : kh - 12;
    const float2* wbase = wsel + (size_t)o * 1728 + xi * 144 + yi * 12 + kw;
    const float2* xbase = Xf + mode;
    float re = 0.f, im = 0.f;
    for (int i = 0; i < 64; i++) {
        float2 xv = xbase[i * 6912];
        float2 wv = wbase[(size_t)i * 110592];       // stride C*1728 float2
        re += xv.x * wv.x - xv.y * wv.y;
        im += xv.x * wv.y + xv.y * wv.x;
    }
    Yf[flat] = make_float2(re, im);
}

// ---------------- inverse D axis: Yf(o,24kd,24,12) -> Zd(o,64d,24,12) ----------------
__global__ void k_inv_d(const float2* __restrict__ Yf, float2* __restrict__ Zd) {
    int flat = blockIdx.x * 256 + threadIdx.x;       // 1,179,648
    int od = flat / 288;
    int r2 = flat - od * 288;
    int o = od >> 6, d = od & 63;
    const float2* base = Yf + o * 6912 + r2;
    float sn, cn;
    sincosf((float)d * STEP64, &sn, &cn);
    float2 st = make_float2(cn, sn);                 // e^{+i theta}
    float2 t = make_float2(1.f, 0.f);
    float re = 0.f, im = 0.f;
#pragma unroll
    for (int kd = 0; kd < 12; kd++) {
        float2 z = base[kd * 288];
        re += z.x * t.x - z.y * t.y;
        im += z.x * t.y + z.y * t.x;
        t = cmul_(t, st);
    }
    float s2, c2;
    sincosf((float)((52 * d) & 63) * STEP64, &s2, &c2);
    t = make_float2(c2, s2);                         // e^{+i*52d*2pi/64}
#pragma unroll
    for (int kd = 12; kd < 24; kd++) {
        float2 z = base[kd * 288];
        re += z.x * t.x - z.y * t.y;
        im += z.x * t.y + z.y * t.x;
        t = cmul_(t, st);
    }
    Zd[flat] = make_float2(re, im);
}

// ---------------- inverse H axis: Zd(od,24kh,12) -> Zh(od,64h,12) ----------------
__global__ void k_inv_h(const float2* __restrict__ Zd, float2* __restrict__ Zh) {
    int flat = blockIdx.x * 256 + threadIdx.x;       // 3,145,728
    int odh = flat / 12;
    int kw = flat - odh * 12;
    int od = odh >> 6, h = odh & 63;
    const float2* base = Zd + od * 288 + kw;
    float sn, cn;
    sincosf((float)h * STEP64, &sn, &cn);
    float2 st = make_float2(cn, sn);
    float2 t = make_float2(1.f, 0.f);
    float re = 0.f, im = 0.f;
#pragma unroll
    for (int kh = 0; kh < 12; kh++) {
        float2 z = base[kh * 12];
        re += z.x * t.x - z.y * t.y;
        im += z.x * t.y + z.y * t.x;
        t = cmul_(t, st);
    }
    float s2, c2;
    sincosf((float)((52 * h) & 63) * STEP64, &s2, &c2);
    t = make_float2(c2, s2);
#pragma unroll
    for (int kh = 12; kh < 24; kh++) {
        float2 z = base[kh * 12];
        re += z.x * t.x - z.y * t.y;
        im += z.x * t.y + z.y * t.x;
        t = cmul_(t, st);
    }
    Zh[flat] = make_float2(re, im);
}

// ---------------- inverse W (irfft, drops Im of DC bin); 4 sites/thread ----------------
__global__ void k_inv_w(const float2* __restrict__ Zh, float* __restrict__ x1) {
    int idx = blockIdx.x * 256 + threadIdx.x;        // 4,194,304
    int row = idx >> 4;
    int w0 = (idx & 15) * 4;
    const float2* base = Zh + row * 12;
    float2 z0 = base[0];
    float acc0 = z0.x, acc1 = z0.x, acc2 = z0.x, acc3 = z0.x;
    float sn, cn;
    sincosf((float)w0 * STEP64, &sn, &cn);
    const float2 e1 = make_float2(0.99518472667219688f, 0.09801714032956060f); // e^{i*2pi/64}
    float2 s0 = make_float2(cn, sn);
    float2 s1 = cmul_(s0, e1);
    float2 s2 = cmul_(s1, e1);
    float2 s3 = cmul_(s2, e1);
    float2 t0 = s0, t1 = s1, t2 = s2, t3 = s3;       // t_j = e^{i*w_j*kw*2pi/64}, kw=1
#pragma unroll
    for (int kw = 1; kw < 12; kw++) {
        float2 z = base[kw];
        acc0 += 2.f * (z.x * t0.x - z.y * t0.y); t0 = cmul_(t0, s0);
        acc1 += 2.f * (z.x * t1.x - z.y * t1.y); t1 = cmul_(t1, s1);
        acc2 += 2.f * (z.x * t2.x - z.y * t2.y); t2 = cmul_(t2, s2);
        acc3 += 2.f * (z.x * t3.x - z.y * t3.y); t3 = cmul_(t3, s3);
    }
    const float sc = 1.0f / 262144.0f;
    *(float4*)(x1 + row * 64 + w0) = make_float4(acc0 * sc, acc1 * sc, acc2 * sc, acc3 * sc);
}

// ---------------- 1x1 conv + bias, accumulate into x1, fused GN stats ----------------
__global__ void k_conv_add(const float* __restrict__ v, float* __restrict__ x1,
                           const float* __restrict__ w, const float* __restrict__ b,
                           float* __restrict__ stats) {
    int s = blockIdx.x * 256 + threadIdx.x;
    float acc[64];
#pragma unroll
    for (int o = 0; o < 64; o++) acc[o] = 0.f;
    for (int i = 0; i < 64; i += 4) {
        float vi0 = v[i * NS + s];
        float vi1 = v[(i + 1) * NS + s];
        float vi2 = v[(i + 2) * NS + s];
        float vi3 = v[(i + 3) * NS + s];
#pragma unroll
        for (int o = 0; o < 64; o++) {
            float4 w4 = *(const float4*)(w + o * 64 + i);   // uniform -> s_load
            acc[o] += w4.x * vi0 + w4.y * vi1 + w4.z * vi2 + w4.w * vi3;
        }
    }
    float gs[16];
#pragma unroll
    for (int g = 0; g < 16; g++) gs[g] = 0.f;
#pragma unroll
    for (int o = 0; o < 64; o++) {
        float t = x1[o * NS + s] + acc[o] + b[o];
        x1[o * NS + s] = t;
        gs[(o >> 3) * 2] += t;
        gs[(o >> 3) * 2 + 1] += t * t;
    }
#pragma unroll
    for (int off = 32; off > 0; off >>= 1) {
#pragma unroll
        for (int g = 0; g < 16; g++) gs[g] += __shfl_down(gs[g], off);
    }
    __shared__ float red[4][16];
    int wid = threadIdx.x >> 6;
    if ((threadIdx.x & 63) == 0) {
#pragma unroll
        for (int g = 0; g < 16; g++) red[wid][g] = gs[g];
    }
    __syncthreads();
    if (threadIdx.x < 16) {
        atomicAdd(&stats[threadIdx.x],
                  red[0][threadIdx.x] + red[1][threadIdx.x] +
                  red[2][threadIdx.x] + red[3][threadIdx.x]);
    }
}

// ---------------- GroupNorm apply + GELU + FiLM -> v ----------------
__global__ void k_gn_apply(const float* __restrict__ x1, float* __restrict__ v,
                           const float* __restrict__ stats, const float* __restrict__ gg,
                           const float* __restrict__ gb, const float* __restrict__ film) {
    int idx = blockIdx.x * 256 + threadIdx.x;        // 16,777,216
    int c = idx >> 18;
    int g = c >> 3;
    float mean = stats[g * 2] * (1.0f / 2097152.0f);
    float var = stats[g * 2 + 1] * (1.0f / 2097152.0f) - mean * mean;
    float inv = rsqrtf(var + 1e-5f);
    float y = (x1[idx] - mean) * inv * gg[c] + gb[c];
    y = gelu_(y);
    float sc = film[c * 2], sh = film[c * 2 + 1];
    v[idx] = y * (1.0f + sc) + sh;
}

// ---------------- fused p1 -> GELU -> p2 epilogue (scalar weight loads) ----------------
__global__ void k_p1p2(const float* __restrict__ v, float* __restrict__ out,
                       const float* __restrict__ w1, const float* __restrict__ b1,
                       const float* __restrict__ w2, const float* __restrict__ b2) {
    int s = blockIdx.x * 256 + threadIdx.x;
    float vv[64];
#pragma unroll
    for (int c = 0; c < 64; c++) vv[c] = v[c * NS + s];
    float a0 = b2[0], a1 = b2[1], a2 = b2[2];
    for (int j = 0; j < 128; j++) {
        float t = b1[j];
        const float* wr = w1 + j * 64;
#pragma unroll
        for (int c = 0; c < 64; c += 4) {
            float4 w4 = *(const float4*)(wr + c);           // uniform -> s_load
            t += w4.x * vv[c] + w4.y * vv[c + 1] + w4.z * vv[c + 2] + w4.w * vv[c + 3];
        }
        t = gelu_(t);
        a0 += t * w2[j];
        a1 += t * w2[128 + j];
        a2 += t * w2[256 + j];
    }
    out[s] = a0;
    out[NS + s] = a1;
    out[2 * NS + s] = a2;
}

extern "C" void kernel_launch(void* const* d_in, const int* in_sizes, int n_in,
                              void* d_out, int out_size, void* d_ws, size_t ws_size,
                              hipStream_t stream) {
    const float* x      = (const float*)d_in[0];
    const float* latent = (const float*)d_in[1];
    const float* lift_w = (const float*)d_in[2];
    const float* lift_b = (const float*)d_in[3];
    const float* sc_w1  = (const float*)d_in[4];
    const float* sc_w2  = (const float*)d_in[5];
    const float* sc_w3  = (const float*)d_in[6];
    const float* sc_w4  = (const float*)d_in[7];
    const float* conv_w = (const float*)d_in[8];
    const float* conv_b = (const float*)d_in[9];
    const float* gn_g   = (const float*)d_in[10];
    const float* gn_b   = (const float*)d_in[11];
    const float* p1_w   = (const float*)d_in[12];
    const float* p1_b   = (const float*)d_in[13];
    const float* p2_w   = (const float*)d_in[14];
    const float* p2_b   = (const float*)d_in[15];
    const float* c1_w   = (const float*)d_in[16];
    const float* c1_b   = (const float*)d_in[17];
    const float* c2_w   = (const float*)d_in[18];
    const float* c2_b   = (const float*)d_in[19];

    float* ws = (float*)d_ws;
    float*  v    = ws;                                // 16,777,216
    float*  x1   = ws + 16777216;                     // 16,777,216
    float2* A    = (float2*)(ws + 33554432);          // 3,145,728 f2 (A / Zh shared)
    float2* Bc   = (float2*)(ws + 39845888);          // 1,179,648 f2 (B / Zd shared)
    float2* Xf   = (float2*)(ws + 42205184);          // 442,368 f2
    float2* Yf   = (float2*)(ws + 43089920);          // 442,368 f2
    float*  hbuf = ws + 43974656;                     // 1024
    float*  film = ws + 43975680;                     // 384
    float*  stats= ws + 43976064;                     // 48

    hipMemsetAsync(stats, 0, 48 * sizeof(float), stream);
    k_film1<<<4, 256, 0, stream>>>(latent, c1_w, c1_b, hbuf);
    k_film2<<<2, 256, 0, stream>>>(hbuf, c2_w, c2_b, film);
    k_lift<<<1024, 256, 0, stream>>>(x, v, lift_w, lift_b);

    for (int l = 0; l < 3; l++) {
        size_t woff = (size_t)l * 64 * 64 * 1728;     // float2 units per layer
        k_fwd_w<<<12288, 256, 0, stream>>>(v, A);
        k_fwd_h<<<4608, 256, 0, stream>>>(A, Bc);
        k_fwd_d<<<1728, 256, 0, stream>>>(Bc, Xf);
        k_modemul<<<1728, 256, 0, stream>>>(Xf, Yf,
            (const float2*)sc_w1 + woff, (const float2*)sc_w2 + woff,
            (const float2*)sc_w3 + woff, (const float2*)sc_w4 + woff);
        k_inv_d<<<4608, 256, 0, stream>>>(Yf, Bc);
        k_inv_h<<<12288, 256, 0, stream>>>(Bc, A);
        k_inv_w<<<16384, 256, 0, stream>>>(A, x1);
        k_conv_add<<<1024, 256, 0, stream>>>(v, x1, conv_w + l * 4096, conv_b + l * 64,
                                             stats + l * 16);
        k_gn_apply<<<65536, 256, 0, stream>>>(x1, v, stats + l * 16,
                                              gn_g + l * 64, gn_b + l * 64, film + l * 128);
    }
    k_p1p2<<<1024, 256, 0, stream>>>(v, (float*)d_out, p1_w, p1_b, p2_w, p2_b);
}